// Round 7
// baseline (161.277 us; speedup 1.0000x reference)
//
#include <hip/hip_runtime.h>
#include <math.h>

#define NPTS 1024
#define HID 64

typedef float v4f __attribute__((ext_vector_type(4)));

// ---------------------------------------------------------------------------
// Kernel A: ONE WAVE per row i. 16 distances/lane in registers (exact fp32
// on the density-count path), packed-int count reduce, 26-iteration
// lexicographic (value,idx) butterfly extraction of the smallest distances
// (lane r keeps knn[r]), in-wave entropies. Zero barriers, zero LDS.
// Exact integer density sums accumulated via ull atomics (deterministic).
// ---------------------------------------------------------------------------
__global__ __launch_bounds__(64) void k_rows(const float* __restrict__ pts,
                                             float* __restrict__ density,
                                             float* __restrict__ ent,
                                             unsigned long long* __restrict__ isums) {
    const int i    = blockIdx.x;
    const int lane = threadIdx.x;

    const float px = pts[i * 3 + 0];
    const float py = pts[i * 3 + 1];
    const float pz = pts[i * 3 + 2];

    // 16 distances per lane, registers only (static indices).
    float v[16];
    int c0 = 0, c1 = 0, c2 = 0;
    #pragma unroll
    for (int q = 0; q < 16; ++q) {
        const int j = lane + q * 64;              // coalesced across lanes
        // exact rounding, no fma contraction: ((dx*dx + dy*dy) + dz*dz)
        float dx = __fsub_rn(px, pts[j * 3 + 0]);
        float dy = __fsub_rn(py, pts[j * 3 + 1]);
        float dz = __fsub_rn(pz, pts[j * 3 + 2]);
        float d2 = __fadd_rn(__fadd_rn(__fmul_rn(dx, dx), __fmul_rn(dy, dy)),
                             __fmul_rn(dz, dz));
        float d = __fsqrt_rn(d2 > 0.0f ? d2 : 1e-12f);   // _safe_sqrt
        v[q] = d;
        c0 += (d < 0.1f);
        c1 += (d < 0.2f);
        c2 += (d < 0.4f);
    }

    // Pack counts into one ull (21-bit fields), single butterfly reduce.
    unsigned long long packed = (unsigned long long)c0
                              | ((unsigned long long)c1 << 21)
                              | ((unsigned long long)c2 << 42);
    #pragma unroll
    for (int off = 32; off > 0; off >>= 1) packed += __shfl_xor(packed, off);
    // every lane now holds the row totals

    // 26 smallest distances; after iteration `it`, lane==it keeps the value.
    float nd = 0.0f;
    for (int it = 0; it < 26; ++it) {
        // local argmin over 16 regs (static unrolled tree)
        float a0[8]; int a0i[8];
        #pragma unroll
        for (int q = 0; q < 8; ++q) {
            bool c = v[2 * q + 1] < v[2 * q];
            a0[q] = c ? v[2 * q + 1] : v[2 * q];
            a0i[q] = c ? 2 * q + 1 : 2 * q;
        }
        float a1[4]; int a1i[4];
        #pragma unroll
        for (int q = 0; q < 4; ++q) {
            bool c = a0[2 * q + 1] < a0[2 * q];
            a1[q] = c ? a0[2 * q + 1] : a0[2 * q];
            a1i[q] = c ? a0i[2 * q + 1] : a0i[2 * q];
        }
        float a2[2]; int a2i[2];
        #pragma unroll
        for (int q = 0; q < 2; ++q) {
            bool c = a1[2 * q + 1] < a1[2 * q];
            a2[q] = c ? a1[2 * q + 1] : a1[2 * q];
            a2i[q] = c ? a1i[2 * q + 1] : a1i[2 * q];
        }
        bool cl = a2[1] < a2[0];
        float m  = cl ? a2[1] : a2[0];
        int   li = cl ? a2i[1] : a2i[0];
        int  idx = (lane << 4) | li;

        // 64-wide lexicographic (value, idx) min — unique winner
        #pragma unroll
        for (int off = 32; off > 0; off >>= 1) {
            float om = __shfl_xor(m, off);
            int   oi = __shfl_xor(idx, off);
            if (om < m || (om == m && oi < idx)) { m = om; idx = oi; }
        }

        const bool win = (idx >> 4) == lane;
        const int  wi  = idx & 15;
        #pragma unroll
        for (int q = 0; q < 16; ++q)
            if (win && wi == q) v[q] = 1e30f;     // invalidate winning slot

        if (it == lane) nd = m;                   // lane r holds knn[r]
    }

    // entropies over ranks 1..k (rank 0 = self)
    const int kv[3] = {5, 10, 25};
    float evals[3];
    #pragma unroll
    for (int q = 0; q < 3; ++q) {
        const int k = kv[q];
        float x = (lane >= 1 && lane <= k) ? nd : 0.0f;
        float S = x;
        #pragma unroll
        for (int off = 32; off > 0; off >>= 1) S += __shfl_xor(S, off);
        float p = x / S;
        float term = (lane >= 1 && lane <= k) ? -p * logf(p + 1e-10f) : 0.0f;
        float E = term;
        #pragma unroll
        for (int off = 32; off > 0; off >>= 1) E += __shfl_xor(E, off);
        evals[q] = E;
    }

    if (lane == 0) {
        ent[i * 3 + 0] = evals[0];
        ent[i * 3 + 1] = evals[1];
        ent[i * 3 + 2] = evals[2];
        const float scl[3] = {0.1f, 0.2f, 0.4f};
        unsigned long long cc[3] = {packed & 0x1FFFFF,
                                    (packed >> 21) & 0x1FFFFF,
                                    (packed >> 42) & 0x1FFFFF};
        #pragma unroll
        for (int s = 0; s < 3; ++s) {
            float sv  = scl[s];
            float vol = __fmul_rn((float)(4.0 / 3.0 * M_PI),
                                  __fmul_rn(__fmul_rn(sv, sv), sv));
            density[i * 3 + s] = (float)cc[s] / vol;
            atomicAdd(&isums[s],     cc[s]);
            atomicAdd(&isums[3 + s], cc[s] * cc[s]);
        }
    }
}

// ---------------------------------------------------------------------------
// Kernel B: fused embed + broadcast. Block (c,g): prologue computes svec
// chunk c (16 rows x 64 hidden) into 4 KB LDS — wave w handles rows
// 16c+4w..16c+4w+3, lane = hidden unit; gradient via exact integer sums
// (fp64 expansion). Then 32 coalesced 4 KB stores to i-group g.
// ---------------------------------------------------------------------------
__global__ __launch_bounds__(256) void k_bcast(const float* __restrict__ density,
                                               const float* __restrict__ ent,
                                               const unsigned long long* __restrict__ isums,
                                               const float* __restrict__ Wm,
                                               const float* __restrict__ bm,
                                               const float* __restrict__ Wl,
                                               const float* __restrict__ bl,
                                               v4f* __restrict__ out) {
    __shared__ float s_lds[16 * HID];
    const int b    = blockIdx.x;
    const int c    = b & 63;          // 64 chunks of 16 rows
    const int g    = b >> 6;          // 32 i-groups of 32 rows
    const int t    = threadIdx.x;
    const int lane = t & 63;
    const int w    = t >> 6;

    // exact sums -> S1, S2 (uniform across block)
    const float scl[3] = {0.1f, 0.2f, 0.4f};
    double S1[3], S2[3];
    #pragma unroll
    for (int s = 0; s < 3; ++s) {
        float sv   = scl[s];
        float volf = __fmul_rn((float)(4.0 / 3.0 * M_PI),
                               __fmul_rn(__fmul_rn(sv, sv), sv));
        double vold = (double)volf;
        S1[s] = (double)isums[s] / vold;
        S2[s] = (double)isums[3 + s] / (vold * vold);
    }

    #pragma unroll
    for (int kk = 0; kk < 4; ++kk) {
        const int row = 16 * c + 4 * w + kk;

        // mdve = l2norm([density(3), gradient(3)])
        float m6[6];
        double nrm6 = 0.0;
        #pragma unroll
        for (int s = 0; s < 3; ++s) {
            float d = density[row * 3 + s];
            m6[s] = d;
            double dd = (double)d;
            double g2 = 1024.0 * dd * dd - 2.0 * dd * S1[s] + S2[s];
            m6[3 + s] = (float)sqrt(g2 > 0.0 ? g2 : 1e-12);
        }
        #pragma unroll
        for (int s = 0; s < 6; ++s) nrm6 += (double)m6[s] * (double)m6[s];
        float inv6 = 1.0f / fmaxf((float)sqrt(nrm6), 1e-12f);
        #pragma unroll
        for (int s = 0; s < 6; ++s) m6[s] *= inv6;

        // lgee = l2norm(entropies(3))
        float l3[3];
        double nrm3 = 0.0;
        #pragma unroll
        for (int s = 0; s < 3; ++s) {
            l3[s] = ent[row * 3 + s];
            nrm3 += (double)l3[s] * (double)l3[s];
        }
        float inv3 = 1.0f / fmaxf((float)sqrt(nrm3), 1e-12f);
        #pragma unroll
        for (int s = 0; s < 3; ++s) l3[s] *= inv3;

        // y = l2norm(mdve @ Wm + bm) over the 64 hidden units (one wave)
        float y = bm[lane];
        #pragma unroll
        for (int s = 0; s < 6; ++s) y += m6[s] * Wm[s * HID + lane];
        float yy = y * y;
        #pragma unroll
        for (int off = 32; off > 0; off >>= 1) yy += __shfl_xor(yy, off);
        y *= 1.0f / fmaxf(sqrtf(yy), 1e-12f);

        // z = l2norm(lgee @ Wl + bl)
        float z = bl[lane];
        #pragma unroll
        for (int s = 0; s < 3; ++s) z += l3[s] * Wl[s * HID + lane];
        float zz = z * z;
        #pragma unroll
        for (int off = 32; off > 0; off >>= 1) zz += __shfl_xor(zz, off);
        z *= 1.0f / fmaxf(sqrtf(zz), 1e-12f);

        s_lds[(4 * w + kk) * HID + lane] = y + z;
    }
    __syncthreads();

    const v4f val = *(const v4f*)&s_lds[4 * t];   // registers

    v4f* dst = out + (size_t)(g * 32) * (NPTS * HID / 4) + c * 256 + t;
    #pragma unroll 4
    for (int ii = 0; ii < 32; ++ii) {
        *dst = val;
        dst += NPTS * HID / 4;                    // next i: +16384 v4f
    }
}

extern "C" void kernel_launch(void* const* d_in, const int* in_sizes, int n_in,
                              void* d_out, int out_size, void* d_ws, size_t ws_size,
                              hipStream_t stream) {
    const float* pts = (const float*)d_in[0];
    // d_in[1], d_in[2] (W_rtdie, b_rtdie) do not affect the output.
    const float* Wm = (const float*)d_in[3];
    const float* bm = (const float*)d_in[4];
    const float* Wl = (const float*)d_in[5];
    const float* bl = (const float*)d_in[6];

    char* ws = (char*)d_ws;
    float* density              = (float*)(ws);                 // 12288 B
    float* entv                 = (float*)(ws + 12288);         // 12288 B
    unsigned long long* isums   = (unsigned long long*)(ws + 24576);  // 48 B

    float* out = (float*)d_out;

    hipMemsetAsync(isums, 0, 6 * sizeof(unsigned long long), stream);
    hipLaunchKernelGGL(k_rows, dim3(NPTS), dim3(64), 0, stream,
                       pts, density, entv, isums);
    hipLaunchKernelGGL(k_bcast, dim3(64 * 32), dim3(256), 0, stream,
                       density, entv, isums, Wm, bm, Wl, bl, (v4f*)out);
}

// Round 9
// 90.213 us; speedup vs baseline: 1.7877x; 1.7877x over previous
//
#include <hip/hip_runtime.h>
#include <math.h>

#define NPTS 1024
#define HID 64

typedef float v4f __attribute__((ext_vector_type(4)));

// ---------------------------------------------------------------------------
// Kernel A: ONE WAVE per row i. 16 distances/lane in registers (exact fp32
// on the density-count path), packed-int count reduce, 26-iteration
// lexicographic (value,idx) butterfly extraction of the smallest distances
// (lane r keeps knn[r]), in-wave entropies. Zero barriers, zero LDS.
// Integer density sums -> 64 BUCKETED cachelines (i&63), ~96 atomics each,
// instead of 6144 same-line atomics (R6's regression).
// ---------------------------------------------------------------------------
__global__ __launch_bounds__(64) void k_rows(const float* __restrict__ pts,
                                             float* __restrict__ density,
                                             float* __restrict__ ent,
                                             unsigned long long* __restrict__ buckets) {
    const int i    = blockIdx.x;
    const int lane = threadIdx.x;

    const float px = pts[i * 3 + 0];
    const float py = pts[i * 3 + 1];
    const float pz = pts[i * 3 + 2];

    // 16 distances per lane, registers only (static indices).
    float v[16];
    int c0 = 0, c1 = 0, c2 = 0;
    #pragma unroll
    for (int q = 0; q < 16; ++q) {
        const int j = lane + q * 64;              // coalesced across lanes
        // exact rounding, no fma contraction: ((dx*dx + dy*dy) + dz*dz)
        float dx = __fsub_rn(px, pts[j * 3 + 0]);
        float dy = __fsub_rn(py, pts[j * 3 + 1]);
        float dz = __fsub_rn(pz, pts[j * 3 + 2]);
        float d2 = __fadd_rn(__fadd_rn(__fmul_rn(dx, dx), __fmul_rn(dy, dy)),
                             __fmul_rn(dz, dz));
        float d = __fsqrt_rn(d2 > 0.0f ? d2 : 1e-12f);   // _safe_sqrt
        v[q] = d;
        c0 += (d < 0.1f);
        c1 += (d < 0.2f);
        c2 += (d < 0.4f);
    }

    // Pack counts into one ull (21-bit fields), single butterfly reduce.
    unsigned long long packed = (unsigned long long)c0
                              | ((unsigned long long)c1 << 21)
                              | ((unsigned long long)c2 << 42);
    #pragma unroll
    for (int off = 32; off > 0; off >>= 1) packed += __shfl_xor(packed, off);
    // every lane now holds the row totals

    // 26 smallest distances; after iteration `it`, lane==it keeps the value.
    float nd = 0.0f;
    for (int it = 0; it < 26; ++it) {
        // local argmin over 16 regs (static unrolled tree)
        float a0[8]; int a0i[8];
        #pragma unroll
        for (int q = 0; q < 8; ++q) {
            bool c = v[2 * q + 1] < v[2 * q];
            a0[q] = c ? v[2 * q + 1] : v[2 * q];
            a0i[q] = c ? 2 * q + 1 : 2 * q;
        }
        float a1[4]; int a1i[4];
        #pragma unroll
        for (int q = 0; q < 4; ++q) {
            bool c = a0[2 * q + 1] < a0[2 * q];
            a1[q] = c ? a0[2 * q + 1] : a0[2 * q];
            a1i[q] = c ? a0i[2 * q + 1] : a0i[2 * q];
        }
        float a2[2]; int a2i[2];
        #pragma unroll
        for (int q = 0; q < 2; ++q) {
            bool c = a1[2 * q + 1] < a1[2 * q];
            a2[q] = c ? a1[2 * q + 1] : a1[2 * q];
            a2i[q] = c ? a1i[2 * q + 1] : a1i[2 * q];
        }
        bool cl = a2[1] < a2[0];
        float m  = cl ? a2[1] : a2[0];
        int   li = cl ? a2i[1] : a2i[0];
        int  idx = (lane << 4) | li;

        // 64-wide lexicographic (value, idx) min — unique winner
        #pragma unroll
        for (int off = 32; off > 0; off >>= 1) {
            float om = __shfl_xor(m, off);
            int   oi = __shfl_xor(idx, off);
            if (om < m || (om == m && oi < idx)) { m = om; idx = oi; }
        }

        const bool win = (idx >> 4) == lane;
        const int  wi  = idx & 15;
        #pragma unroll
        for (int q = 0; q < 16; ++q)
            if (win && wi == q) v[q] = 1e30f;     // invalidate winning slot

        if (it == lane) nd = m;                   // lane r holds knn[r]
    }

    // entropies over ranks 1..k (rank 0 = self)
    const int kv[3] = {5, 10, 25};
    float evals[3];
    #pragma unroll
    for (int q = 0; q < 3; ++q) {
        const int k = kv[q];
        float x = (lane >= 1 && lane <= k) ? nd : 0.0f;
        float S = x;
        #pragma unroll
        for (int off = 32; off > 0; off >>= 1) S += __shfl_xor(S, off);
        float p = x / S;
        float term = (lane >= 1 && lane <= k) ? -p * logf(p + 1e-10f) : 0.0f;
        float E = term;
        #pragma unroll
        for (int off = 32; off > 0; off >>= 1) E += __shfl_xor(E, off);
        evals[q] = E;
    }

    if (lane == 0) {
        ent[i * 3 + 0] = evals[0];
        ent[i * 3 + 1] = evals[1];
        ent[i * 3 + 2] = evals[2];
        const float scl[3] = {0.1f, 0.2f, 0.4f};
        unsigned long long cc[3] = {packed & 0x1FFFFF,
                                    (packed >> 21) & 0x1FFFFF,
                                    (packed >> 42) & 0x1FFFFF};
        unsigned long long* bp = &buckets[(i & 63) * 16];  // 128 B apart
        #pragma unroll
        for (int s = 0; s < 3; ++s) {
            float sv  = scl[s];
            float vol = __fmul_rn((float)(4.0 / 3.0 * M_PI),
                                  __fmul_rn(__fmul_rn(sv, sv), sv));
            density[i * 3 + s] = (float)cc[s] / vol;
            atomicAdd(&bp[s],     cc[s]);
            atomicAdd(&bp[3 + s], cc[s] * cc[s]);
        }
    }
}

// ---------------------------------------------------------------------------
// Kernel B: fused embed + broadcast. Wave 0 reduces the 64 sum-buckets ->
// LDS (S1,S2 exact-integer based). Block (c,g): computes svec chunk c
// (16 rows x 64 hidden) into 4 KB LDS, then 32 coalesced 4 KB stores.
// ---------------------------------------------------------------------------
__global__ __launch_bounds__(256) void k_bcast(const float* __restrict__ density,
                                               const float* __restrict__ ent,
                                               const unsigned long long* __restrict__ buckets,
                                               const float* __restrict__ Wm,
                                               const float* __restrict__ bm,
                                               const float* __restrict__ Wl,
                                               const float* __restrict__ bl,
                                               v4f* __restrict__ out) {
    __shared__ float  s_lds[16 * HID];
    __shared__ double sS[6];           // S1[0..2], S2[0..2]
    const int b    = blockIdx.x;
    const int c    = b & 63;           // 64 chunks of 16 rows
    const int g    = b >> 6;           // 32 i-groups of 32 rows
    const int t    = threadIdx.x;
    const int lane = t & 63;
    const int w    = t >> 6;

    // wave 0: reduce 64 buckets (one per lane) -> exact integer sums -> S1,S2
    if (w == 0) {
        const unsigned long long* bp = &buckets[lane * 16];
        unsigned long long a[6];
        #pragma unroll
        for (int s = 0; s < 6; ++s) a[s] = bp[s];
        #pragma unroll
        for (int off = 32; off > 0; off >>= 1) {
            #pragma unroll
            for (int s = 0; s < 6; ++s) a[s] += __shfl_xor(a[s], off);
        }
        if (lane < 3) {
            const float scl[3] = {0.1f, 0.2f, 0.4f};
            float sv   = scl[lane];
            float volf = __fmul_rn((float)(4.0 / 3.0 * M_PI),
                                   __fmul_rn(__fmul_rn(sv, sv), sv));
            double vold = (double)volf;
            sS[lane]     = (double)a[lane] / vold;                 // S1
            sS[3 + lane] = (double)a[3 + lane] / (vold * vold);    // S2
        }
    }
    __syncthreads();

    double S1[3], S2[3];
    #pragma unroll
    for (int s = 0; s < 3; ++s) { S1[s] = sS[s]; S2[s] = sS[3 + s]; }

    #pragma unroll
    for (int kk = 0; kk < 4; ++kk) {
        const int row = 16 * c + 4 * w + kk;

        // mdve = l2norm([density(3), gradient(3)])
        float m6[6];
        double nrm6 = 0.0;
        #pragma unroll
        for (int s = 0; s < 3; ++s) {
            float d = density[row * 3 + s];
            m6[s] = d;
            double dd = (double)d;
            double g2 = 1024.0 * dd * dd - 2.0 * dd * S1[s] + S2[s];
            m6[3 + s] = (float)sqrt(g2 > 0.0 ? g2 : 1e-12);
        }
        #pragma unroll
        for (int s = 0; s < 6; ++s) nrm6 += (double)m6[s] * (double)m6[s];
        float inv6 = 1.0f / fmaxf((float)sqrt(nrm6), 1e-12f);
        #pragma unroll
        for (int s = 0; s < 6; ++s) m6[s] *= inv6;

        // lgee = l2norm(entropies(3))
        float l3[3];
        double nrm3 = 0.0;
        #pragma unroll
        for (int s = 0; s < 3; ++s) {
            l3[s] = ent[row * 3 + s];
            nrm3 += (double)l3[s] * (double)l3[s];
        }
        float inv3 = 1.0f / fmaxf((float)sqrt(nrm3), 1e-12f);
        #pragma unroll
        for (int s = 0; s < 3; ++s) l3[s] *= inv3;

        // y = l2norm(mdve @ Wm + bm) over the 64 hidden units (one wave)
        float y = bm[lane];
        #pragma unroll
        for (int s = 0; s < 6; ++s) y += m6[s] * Wm[s * HID + lane];
        float yy = y * y;
        #pragma unroll
        for (int off = 32; off > 0; off >>= 1) yy += __shfl_xor(yy, off);
        y *= 1.0f / fmaxf(sqrtf(yy), 1e-12f);

        // z = l2norm(lgee @ Wl + bl)
        float z = bl[lane];
        #pragma unroll
        for (int s = 0; s < 3; ++s) z += l3[s] * Wl[s * HID + lane];
        float zz = z * z;
        #pragma unroll
        for (int off = 32; off > 0; off >>= 1) zz += __shfl_xor(zz, off);
        z *= 1.0f / fmaxf(sqrtf(zz), 1e-12f);

        s_lds[(4 * w + kk) * HID + lane] = y + z;
    }
    __syncthreads();

    const v4f val = *(const v4f*)&s_lds[4 * t];   // registers

    v4f* dst = out + (size_t)(g * 32) * (NPTS * HID / 4) + c * 256 + t;
    #pragma unroll 4
    for (int ii = 0; ii < 32; ++ii) {
        *dst = val;
        dst += NPTS * HID / 4;                    // next i: +16384 v4f
    }
}

extern "C" void kernel_launch(void* const* d_in, const int* in_sizes, int n_in,
                              void* d_out, int out_size, void* d_ws, size_t ws_size,
                              hipStream_t stream) {
    const float* pts = (const float*)d_in[0];
    // d_in[1], d_in[2] (W_rtdie, b_rtdie) do not affect the output.
    const float* Wm = (const float*)d_in[3];
    const float* bm = (const float*)d_in[4];
    const float* Wl = (const float*)d_in[5];
    const float* bl = (const float*)d_in[6];

    char* ws = (char*)d_ws;
    float* density            = (float*)(ws);                        // 12288 B
    float* entv               = (float*)(ws + 12288);                // 12288 B
    unsigned long long* bkts  = (unsigned long long*)(ws + 24576);   // 8192 B

    float* out = (float*)d_out;

    hipMemsetAsync(bkts, 0, 64 * 16 * sizeof(unsigned long long), stream);
    hipLaunchKernelGGL(k_rows, dim3(NPTS), dim3(64), 0, stream,
                       pts, density, entv, bkts);
    hipLaunchKernelGGL(k_bcast, dim3(64 * 32), dim3(256), 0, stream,
                       density, entv, bkts, Wm, bm, Wl, bl, (v4f*)out);
}

// Round 11
// 83.702 us; speedup vs baseline: 1.9268x; 1.0778x over previous
//
#include <hip/hip_runtime.h>
#include <math.h>

#define NPTS 1024
#define HID 64

typedef float v4f __attribute__((ext_vector_type(4)));

// ---------------------------------------------------------------------------
// Kernel A: ONE WAVE per row i. 16 distances/lane in registers (exact fp32
// on the density-count path), packed-int count reduce, 26-iteration
// lexicographic (value,idx) butterfly extraction of the smallest distances
// (lane r keeps knn[r]), in-wave entropies. Zero barriers, zero LDS,
// ZERO atomics: per-row integer counts written directly to icnt.
// ---------------------------------------------------------------------------
__global__ __launch_bounds__(64) void k_rows(const float* __restrict__ pts,
                                             float* __restrict__ density,
                                             float* __restrict__ ent,
                                             unsigned int* __restrict__ icnt) {
    const int i    = blockIdx.x;
    const int lane = threadIdx.x;

    const float px = pts[i * 3 + 0];
    const float py = pts[i * 3 + 1];
    const float pz = pts[i * 3 + 2];

    // 16 distances per lane, registers only (static indices).
    float v[16];
    int c0 = 0, c1 = 0, c2 = 0;
    #pragma unroll
    for (int q = 0; q < 16; ++q) {
        const int j = lane + q * 64;              // coalesced across lanes
        // exact rounding, no fma contraction: ((dx*dx + dy*dy) + dz*dz)
        float dx = __fsub_rn(px, pts[j * 3 + 0]);
        float dy = __fsub_rn(py, pts[j * 3 + 1]);
        float dz = __fsub_rn(pz, pts[j * 3 + 2]);
        float d2 = __fadd_rn(__fadd_rn(__fmul_rn(dx, dx), __fmul_rn(dy, dy)),
                             __fmul_rn(dz, dz));
        float d = __fsqrt_rn(d2 > 0.0f ? d2 : 1e-12f);   // _safe_sqrt
        v[q] = d;
        c0 += (d < 0.1f);
        c1 += (d < 0.2f);
        c2 += (d < 0.4f);
    }

    // Pack counts into one ull (21-bit fields), single butterfly reduce.
    unsigned long long packed = (unsigned long long)c0
                              | ((unsigned long long)c1 << 21)
                              | ((unsigned long long)c2 << 42);
    #pragma unroll
    for (int off = 32; off > 0; off >>= 1) packed += __shfl_xor(packed, off);
    // every lane now holds the row totals

    // 26 smallest distances; after iteration `it`, lane==it keeps the value.
    float nd = 0.0f;
    for (int it = 0; it < 26; ++it) {
        // local argmin over 16 regs (static unrolled tree)
        float a0[8]; int a0i[8];
        #pragma unroll
        for (int q = 0; q < 8; ++q) {
            bool c = v[2 * q + 1] < v[2 * q];
            a0[q]  = c ? v[2 * q + 1] : v[2 * q];
            a0i[q] = c ? 2 * q + 1 : 2 * q;
        }
        float a1[4]; int a1i[4];
        #pragma unroll
        for (int q = 0; q < 4; ++q) {
            bool c = a0[2 * q + 1] < a0[2 * q];
            a1[q]  = c ? a0[2 * q + 1] : a0[2 * q];
            a1i[q] = c ? a0i[2 * q + 1] : a0i[2 * q];
        }
        float a2[2]; int a2i[2];
        #pragma unroll
        for (int q = 0; q < 2; ++q) {
            bool c = a1[2 * q + 1] < a1[2 * q];
            a2[q]  = c ? a1[2 * q + 1] : a1[2 * q];
            a2i[q] = c ? a1i[2 * q + 1] : a1i[2 * q];
        }
        bool cl  = a2[1] < a2[0];
        float m  = cl ? a2[1] : a2[0];
        int   li = cl ? a2i[1] : a2i[0];
        int  idx = (lane << 4) | li;

        // 64-wide lexicographic (value, idx) min — unique winner
        #pragma unroll
        for (int off = 32; off > 0; off >>= 1) {
            float om = __shfl_xor(m, off);
            int   oi = __shfl_xor(idx, off);
            if (om < m || (om == m && oi < idx)) { m = om; idx = oi; }
        }

        const bool win = (idx >> 4) == lane;
        const int  wi  = idx & 15;
        #pragma unroll
        for (int q = 0; q < 16; ++q)
            if (win && wi == q) v[q] = 1e30f;     // invalidate winning slot

        if (it == lane) nd = m;                   // lane r holds knn[r]
    }

    // entropies over ranks 1..k (rank 0 = self)
    const int kv[3] = {5, 10, 25};
    float evals[3];
    #pragma unroll
    for (int q = 0; q < 3; ++q) {
        const int k = kv[q];
        float x = (lane >= 1 && lane <= k) ? nd : 0.0f;
        float S = x;
        #pragma unroll
        for (int off = 32; off > 0; off >>= 1) S += __shfl_xor(S, off);
        float p = x / S;
        float term = (lane >= 1 && lane <= k) ? -p * logf(p + 1e-10f) : 0.0f;
        float E = term;
        #pragma unroll
        for (int off = 32; off > 0; off >>= 1) E += __shfl_xor(E, off);
        evals[q] = E;
    }

    if (lane == 0) {
        ent[i * 3 + 0] = evals[0];
        ent[i * 3 + 1] = evals[1];
        ent[i * 3 + 2] = evals[2];
        const float scl[3] = {0.1f, 0.2f, 0.4f};
        unsigned int cc[3] = {(unsigned int)(packed & 0x1FFFFF),
                              (unsigned int)((packed >> 21) & 0x1FFFFF),
                              (unsigned int)(packed >> 42)};
        #pragma unroll
        for (int s = 0; s < 3; ++s) {
            float sv  = scl[s];
            float vol = __fmul_rn((float)(4.0 / 3.0 * M_PI),
                                  __fmul_rn(__fmul_rn(sv, sv), sv));
            density[i * 3 + s] = (float)cc[s] / vol;
            icnt[i * 3 + s] = cc[s];
        }
    }
}

// ---------------------------------------------------------------------------
// Kernel B: fused embed + broadcast. Wave 0 reduces the 1024x3 integer
// counts (16 rows/lane, exact u32) -> S1,S2 in LDS. Block (c,g): computes
// svec chunk c (16 rows x 64 hidden) into 4 KB LDS, then 32 coalesced
// 4 KB stores to i-group g.
// ---------------------------------------------------------------------------
__global__ __launch_bounds__(256) void k_bcast(const float* __restrict__ density,
                                               const float* __restrict__ ent,
                                               const unsigned int* __restrict__ icnt,
                                               const float* __restrict__ Wm,
                                               const float* __restrict__ bm,
                                               const float* __restrict__ Wl,
                                               const float* __restrict__ bl,
                                               v4f* __restrict__ out) {
    __shared__ float  s_lds[16 * HID];
    __shared__ double sS[6];           // S1[0..2], S2[0..2]
    const int b    = blockIdx.x;
    const int c    = b & 63;           // 64 chunks of 16 rows
    const int g    = b >> 6;           // 32 i-groups of 32 rows
    const int t    = threadIdx.x;
    const int lane = t & 63;
    const int w    = t >> 6;

    // wave 0: exact integer sums over all rows (lane owns rows lane*16..+15)
    if (w == 0) {
        unsigned int sa0 = 0, sa1 = 0, sa2 = 0, sb0 = 0, sb1 = 0, sb2 = 0;
        #pragma unroll
        for (int r = 0; r < 16; ++r) {
            const int row = lane * 16 + r;
            unsigned int c0 = icnt[row * 3 + 0];
            unsigned int c1 = icnt[row * 3 + 1];
            unsigned int c2 = icnt[row * 3 + 2];
            sa0 += c0; sa1 += c1; sa2 += c2;
            sb0 += c0 * c0; sb1 += c1 * c1; sb2 += c2 * c2;
        }
        #pragma unroll
        for (int off = 32; off > 0; off >>= 1) {
            sa0 += __shfl_xor(sa0, off); sa1 += __shfl_xor(sa1, off);
            sa2 += __shfl_xor(sa2, off); sb0 += __shfl_xor(sb0, off);
            sb1 += __shfl_xor(sb1, off); sb2 += __shfl_xor(sb2, off);
        }
        if (lane == 0) {
            const float scl[3] = {0.1f, 0.2f, 0.4f};
            unsigned int A[3] = {sa0, sa1, sa2};
            unsigned int B[3] = {sb0, sb1, sb2};
            #pragma unroll
            for (int s = 0; s < 3; ++s) {
                float sv   = scl[s];
                float volf = __fmul_rn((float)(4.0 / 3.0 * M_PI),
                                       __fmul_rn(__fmul_rn(sv, sv), sv));
                double vold = (double)volf;
                sS[s]     = (double)A[s] / vold;
                sS[3 + s] = (double)B[s] / (vold * vold);
            }
        }
    }
    __syncthreads();

    double S1[3], S2[3];
    #pragma unroll
    for (int s = 0; s < 3; ++s) { S1[s] = sS[s]; S2[s] = sS[3 + s]; }

    #pragma unroll
    for (int kk = 0; kk < 4; ++kk) {
        const int row = 16 * c + 4 * w + kk;

        // mdve = l2norm([density(3), gradient(3)])
        float m6[6];
        double nrm6 = 0.0;
        #pragma unroll
        for (int s = 0; s < 3; ++s) {
            float d = density[row * 3 + s];
            m6[s] = d;
            double dd = (double)d;
            double g2 = 1024.0 * dd * dd - 2.0 * dd * S1[s] + S2[s];
            m6[3 + s] = (float)sqrt(g2 > 0.0 ? g2 : 1e-12);
        }
        #pragma unroll
        for (int s = 0; s < 6; ++s) nrm6 += (double)m6[s] * (double)m6[s];
        float inv6 = 1.0f / fmaxf((float)sqrt(nrm6), 1e-12f);
        #pragma unroll
        for (int s = 0; s < 6; ++s) m6[s] *= inv6;

        // lgee = l2norm(entropies(3))
        float l3[3];
        double nrm3 = 0.0;
        #pragma unroll
        for (int s = 0; s < 3; ++s) {
            l3[s] = ent[row * 3 + s];
            nrm3 += (double)l3[s] * (double)l3[s];
        }
        float inv3 = 1.0f / fmaxf((float)sqrt(nrm3), 1e-12f);
        #pragma unroll
        for (int s = 0; s < 3; ++s) l3[s] *= inv3;

        // y = l2norm(mdve @ Wm + bm) over the 64 hidden units (one wave)
        float y = bm[lane];
        #pragma unroll
        for (int s = 0; s < 6; ++s) y += m6[s] * Wm[s * HID + lane];
        float yy = y * y;
        #pragma unroll
        for (int off = 32; off > 0; off >>= 1) yy += __shfl_xor(yy, off);
        y *= 1.0f / fmaxf(sqrtf(yy), 1e-12f);

        // z = l2norm(lgee @ Wl + bl)
        float z = bl[lane];
        #pragma unroll
        for (int s = 0; s < 3; ++s) z += l3[s] * Wl[s * HID + lane];
        float zz = z * z;
        #pragma unroll
        for (int off = 32; off > 0; off >>= 1) zz += __shfl_xor(zz, off);
        z *= 1.0f / fmaxf(sqrtf(zz), 1e-12f);

        s_lds[(4 * w + kk) * HID + lane] = y + z;
    }
    __syncthreads();

    const v4f val = *(const v4f*)&s_lds[4 * t];   // registers

    v4f* dst = out + (size_t)(g * 32) * (NPTS * HID / 4) + c * 256 + t;
    #pragma unroll 4
    for (int ii = 0; ii < 32; ++ii) {
        *dst = val;
        dst += NPTS * HID / 4;                    // next i: +16384 v4f
    }
}

extern "C" void kernel_launch(void* const* d_in, const int* in_sizes, int n_in,
                              void* d_out, int out_size, void* d_ws, size_t ws_size,
                              hipStream_t stream) {
    const float* pts = (const float*)d_in[0];
    // d_in[1], d_in[2] (W_rtdie, b_rtdie) do not affect the output.
    const float* Wm = (const float*)d_in[3];
    const float* bm = (const float*)d_in[4];
    const float* Wl = (const float*)d_in[5];
    const float* bl = (const float*)d_in[6];

    char* ws = (char*)d_ws;
    float*        density = (float*)(ws);                 // 12288 B
    float*        entv    = (float*)(ws + 12288);         // 12288 B
    unsigned int* icnt    = (unsigned int*)(ws + 24576);  // 12288 B

    float* out = (float*)d_out;

    hipLaunchKernelGGL(k_rows, dim3(NPTS), dim3(64), 0, stream,
                       pts, density, entv, icnt);
    hipLaunchKernelGGL(k_bcast, dim3(64 * 32), dim3(256), 0, stream,
                       density, entv, icnt, Wm, bm, Wl, bl, (v4f*)out);
}

// Round 12
// 83.095 us; speedup vs baseline: 1.9409x; 1.0073x over previous
//
#include <hip/hip_runtime.h>
#include <math.h>

#define NPTS 1024
#define HID 64

typedef float v4f __attribute__((ext_vector_type(4)));

// ---------------------------------------------------------------------------
// Kernel A: ONE WAVE per row i. 16 distances/lane in registers (exact fp32
// on the density-count path), packed-int count reduce, 26-iteration
// lexicographic (value,idx) butterfly extraction of the smallest distances
// (lane r keeps knn[r]), in-wave entropies. Zero barriers, zero LDS, zero
// atomics: per-row integer counts written directly to icnt.
// ---------------------------------------------------------------------------
__global__ __launch_bounds__(64) void k_rows(const float* __restrict__ pts,
                                             float* __restrict__ density,
                                             float* __restrict__ ent,
                                             unsigned int* __restrict__ icnt) {
    const int i    = blockIdx.x;
    const int lane = threadIdx.x;

    const float px = pts[i * 3 + 0];
    const float py = pts[i * 3 + 1];
    const float pz = pts[i * 3 + 2];

    // 16 distances per lane, registers only (static indices).
    float v[16];
    int c0 = 0, c1 = 0, c2 = 0;
    #pragma unroll
    for (int q = 0; q < 16; ++q) {
        const int j = lane + q * 64;              // coalesced across lanes
        // exact rounding, no fma contraction: ((dx*dx + dy*dy) + dz*dz)
        float dx = __fsub_rn(px, pts[j * 3 + 0]);
        float dy = __fsub_rn(py, pts[j * 3 + 1]);
        float dz = __fsub_rn(pz, pts[j * 3 + 2]);
        float d2 = __fadd_rn(__fadd_rn(__fmul_rn(dx, dx), __fmul_rn(dy, dy)),
                             __fmul_rn(dz, dz));
        float d = __fsqrt_rn(d2 > 0.0f ? d2 : 1e-12f);   // _safe_sqrt
        v[q] = d;
        c0 += (d < 0.1f);
        c1 += (d < 0.2f);
        c2 += (d < 0.4f);
    }

    // Pack counts into one ull (21-bit fields), single butterfly reduce.
    unsigned long long packed = (unsigned long long)c0
                              | ((unsigned long long)c1 << 21)
                              | ((unsigned long long)c2 << 42);
    #pragma unroll
    for (int off = 32; off > 0; off >>= 1) packed += __shfl_xor(packed, off);
    // every lane now holds the row totals

    // 26 smallest distances; after iteration `it`, lane==it keeps the value.
    float nd = 0.0f;
    for (int it = 0; it < 26; ++it) {
        // local argmin over 16 regs (static unrolled tree)
        float a0[8]; int a0i[8];
        #pragma unroll
        for (int q = 0; q < 8; ++q) {
            bool c = v[2 * q + 1] < v[2 * q];
            a0[q]  = c ? v[2 * q + 1] : v[2 * q];
            a0i[q] = c ? 2 * q + 1 : 2 * q;
        }
        float a1[4]; int a1i[4];
        #pragma unroll
        for (int q = 0; q < 4; ++q) {
            bool c = a0[2 * q + 1] < a0[2 * q];
            a1[q]  = c ? a0[2 * q + 1] : a0[2 * q];
            a1i[q] = c ? a0i[2 * q + 1] : a0i[2 * q];
        }
        float a2[2]; int a2i[2];
        #pragma unroll
        for (int q = 0; q < 2; ++q) {
            bool c = a1[2 * q + 1] < a1[2 * q];
            a2[q]  = c ? a1[2 * q + 1] : a1[2 * q];
            a2i[q] = c ? a1i[2 * q + 1] : a1i[2 * q];
        }
        bool cl  = a2[1] < a2[0];
        float m  = cl ? a2[1] : a2[0];
        int   li = cl ? a2i[1] : a2i[0];
        int  idx = (lane << 4) | li;

        // 64-wide lexicographic (value, idx) min — unique winner
        #pragma unroll
        for (int off = 32; off > 0; off >>= 1) {
            float om = __shfl_xor(m, off);
            int   oi = __shfl_xor(idx, off);
            if (om < m || (om == m && oi < idx)) { m = om; idx = oi; }
        }

        const bool win = (idx >> 4) == lane;
        const int  wi  = idx & 15;
        #pragma unroll
        for (int q = 0; q < 16; ++q)
            if (win && wi == q) v[q] = 1e30f;     // invalidate winning slot

        if (it == lane) nd = m;                   // lane r holds knn[r]
    }

    // entropies over ranks 1..k (rank 0 = self)
    const int kv[3] = {5, 10, 25};
    float evals[3];
    #pragma unroll
    for (int q = 0; q < 3; ++q) {
        const int k = kv[q];
        float x = (lane >= 1 && lane <= k) ? nd : 0.0f;
        float S = x;
        #pragma unroll
        for (int off = 32; off > 0; off >>= 1) S += __shfl_xor(S, off);
        float p = x / S;
        float term = (lane >= 1 && lane <= k) ? -p * logf(p + 1e-10f) : 0.0f;
        float E = term;
        #pragma unroll
        for (int off = 32; off > 0; off >>= 1) E += __shfl_xor(E, off);
        evals[q] = E;
    }

    if (lane == 0) {
        ent[i * 3 + 0] = evals[0];
        ent[i * 3 + 1] = evals[1];
        ent[i * 3 + 2] = evals[2];
        const float scl[3] = {0.1f, 0.2f, 0.4f};
        unsigned int cc[3] = {(unsigned int)(packed & 0x1FFFFF),
                              (unsigned int)((packed >> 21) & 0x1FFFFF),
                              (unsigned int)(packed >> 42)};
        #pragma unroll
        for (int s = 0; s < 3; ++s) {
            float sv  = scl[s];
            float vol = __fmul_rn((float)(4.0 / 3.0 * M_PI),
                                  __fmul_rn(__fmul_rn(sv, sv), sv));
            density[i * 3 + s] = (float)cc[s] / vol;
            icnt[i * 3 + s] = cc[s];
        }
    }
}

// ---------------------------------------------------------------------------
// Kernel B: embed only. 64 blocks x 256 thr; wave 0 reduces the 1024x3
// integer counts -> exact S1,S2; each wave embeds 4 rows -> svec (global).
// 32x less redundancy than the fused R11 version.
// ---------------------------------------------------------------------------
__global__ __launch_bounds__(256) void k_embed(const float* __restrict__ density,
                                               const float* __restrict__ ent,
                                               const unsigned int* __restrict__ icnt,
                                               const float* __restrict__ Wm,
                                               const float* __restrict__ bm,
                                               const float* __restrict__ Wl,
                                               const float* __restrict__ bl,
                                               float* __restrict__ svec) {
    __shared__ double sS[6];           // S1[0..2], S2[0..2]
    const int c    = blockIdx.x;       // chunk of 16 rows
    const int t    = threadIdx.x;
    const int lane = t & 63;
    const int w    = t >> 6;

    // wave 0: exact integer sums over all rows (lane owns rows lane*16..+15)
    if (w == 0) {
        unsigned int sa0 = 0, sa1 = 0, sa2 = 0, sb0 = 0, sb1 = 0, sb2 = 0;
        #pragma unroll
        for (int r = 0; r < 16; ++r) {
            const int row = lane * 16 + r;
            unsigned int c0 = icnt[row * 3 + 0];
            unsigned int c1 = icnt[row * 3 + 1];
            unsigned int c2 = icnt[row * 3 + 2];
            sa0 += c0; sa1 += c1; sa2 += c2;
            sb0 += c0 * c0; sb1 += c1 * c1; sb2 += c2 * c2;
        }
        #pragma unroll
        for (int off = 32; off > 0; off >>= 1) {
            sa0 += __shfl_xor(sa0, off); sa1 += __shfl_xor(sa1, off);
            sa2 += __shfl_xor(sa2, off); sb0 += __shfl_xor(sb0, off);
            sb1 += __shfl_xor(sb1, off); sb2 += __shfl_xor(sb2, off);
        }
        if (lane == 0) {
            const float scl[3] = {0.1f, 0.2f, 0.4f};
            unsigned int A[3] = {sa0, sa1, sa2};
            unsigned int B[3] = {sb0, sb1, sb2};
            #pragma unroll
            for (int s = 0; s < 3; ++s) {
                float sv   = scl[s];
                float volf = __fmul_rn((float)(4.0 / 3.0 * M_PI),
                                       __fmul_rn(__fmul_rn(sv, sv), sv));
                double vold = (double)volf;
                sS[s]     = (double)A[s] / vold;
                sS[3 + s] = (double)B[s] / (vold * vold);
            }
        }
    }
    __syncthreads();

    double S1[3], S2[3];
    #pragma unroll
    for (int s = 0; s < 3; ++s) { S1[s] = sS[s]; S2[s] = sS[3 + s]; }

    #pragma unroll
    for (int kk = 0; kk < 4; ++kk) {
        const int row = 16 * c + 4 * w + kk;

        // mdve = l2norm([density(3), gradient(3)])
        float m6[6];
        double nrm6 = 0.0;
        #pragma unroll
        for (int s = 0; s < 3; ++s) {
            float d = density[row * 3 + s];
            m6[s] = d;
            double dd = (double)d;
            double g2 = 1024.0 * dd * dd - 2.0 * dd * S1[s] + S2[s];
            m6[3 + s] = (float)sqrt(g2 > 0.0 ? g2 : 1e-12);
        }
        #pragma unroll
        for (int s = 0; s < 6; ++s) nrm6 += (double)m6[s] * (double)m6[s];
        float inv6 = 1.0f / fmaxf((float)sqrt(nrm6), 1e-12f);
        #pragma unroll
        for (int s = 0; s < 6; ++s) m6[s] *= inv6;

        // lgee = l2norm(entropies(3))
        float l3[3];
        double nrm3 = 0.0;
        #pragma unroll
        for (int s = 0; s < 3; ++s) {
            l3[s] = ent[row * 3 + s];
            nrm3 += (double)l3[s] * (double)l3[s];
        }
        float inv3 = 1.0f / fmaxf((float)sqrt(nrm3), 1e-12f);
        #pragma unroll
        for (int s = 0; s < 3; ++s) l3[s] *= inv3;

        // y = l2norm(mdve @ Wm + bm) over the 64 hidden units (one wave)
        float y = bm[lane];
        #pragma unroll
        for (int s = 0; s < 6; ++s) y += m6[s] * Wm[s * HID + lane];
        float yy = y * y;
        #pragma unroll
        for (int off = 32; off > 0; off >>= 1) yy += __shfl_xor(yy, off);
        y *= 1.0f / fmaxf(sqrtf(yy), 1e-12f);

        // z = l2norm(lgee @ Wl + bl)
        float z = bl[lane];
        #pragma unroll
        for (int s = 0; s < 3; ++s) z += l3[s] * Wl[s * HID + lane];
        float zz = z * z;
        #pragma unroll
        for (int off = 32; off > 0; off >>= 1) zz += __shfl_xor(zz, off);
        z *= 1.0f / fmaxf(sqrtf(zz), 1e-12f);

        svec[row * HID + lane] = y + z;
    }
}

// ---------------------------------------------------------------------------
// Kernel C: PURE broadcast — sequential grid-stride write stream (the R4
// pattern), source svec stays L2-resident. Isolates store bandwidth.
// ---------------------------------------------------------------------------
__global__ __launch_bounds__(256) void k_bcast(const v4f* __restrict__ s4,
                                               v4f* __restrict__ out) {
    const int total = (NPTS * NPTS * HID) / 4;       // 16,777,216 v4f
    const int mask  = (NPTS * HID) / 4 - 1;          // 16383
    int idx = blockIdx.x * 256 + threadIdx.x;
    const int stride = gridDim.x * 256;
    for (; idx < total; idx += stride) {
        out[idx] = s4[idx & mask];
    }
}

extern "C" void kernel_launch(void* const* d_in, const int* in_sizes, int n_in,
                              void* d_out, int out_size, void* d_ws, size_t ws_size,
                              hipStream_t stream) {
    const float* pts = (const float*)d_in[0];
    // d_in[1], d_in[2] (W_rtdie, b_rtdie) do not affect the output.
    const float* Wm = (const float*)d_in[3];
    const float* bm = (const float*)d_in[4];
    const float* Wl = (const float*)d_in[5];
    const float* bl = (const float*)d_in[6];

    char* ws = (char*)d_ws;
    float*        density = (float*)(ws);                 // 12288 B
    float*        entv    = (float*)(ws + 12288);         // 12288 B
    unsigned int* icnt    = (unsigned int*)(ws + 24576);  // 12288 B
    float*        svec    = (float*)(ws + 36864);         // 262144 B

    float* out = (float*)d_out;

    hipLaunchKernelGGL(k_rows, dim3(NPTS), dim3(64), 0, stream,
                       pts, density, entv, icnt);
    hipLaunchKernelGGL(k_embed, dim3(64), dim3(256), 0, stream,
                       density, entv, icnt, Wm, bm, Wl, bl, svec);
    hipLaunchKernelGGL(k_bcast, dim3(2048), dim3(256), 0, stream,
                       (const v4f*)svec, (v4f*)out);
}

// Round 13
// 69.796 us; speedup vs baseline: 2.3107x; 1.1906x over previous
//
#include <hip/hip_runtime.h>
#include <math.h>

#define NPTS 1024
#define HID 64

typedef float v4f __attribute__((ext_vector_type(4)));

// ---------------------------------------------------------------------------
// Kernel A: ONE WAVE per row i. 16 distances/lane (exact fp32 on the
// density-count path). Selection of the 26 smallest via per-lane bitonic
// sort(16) + 6-step butterfly keep-min-32 merge (value multiset — exact).
// Every lane ends with the global sorted 32 smallest in registers; entropies
// are then pure per-lane VALU. Dependent-shfl depth: 6 (was 26x6).
// ---------------------------------------------------------------------------
__global__ __launch_bounds__(64) void k_rows(const float* __restrict__ pts,
                                             float* __restrict__ density,
                                             float* __restrict__ ent,
                                             unsigned int* __restrict__ icnt) {
    const int i    = blockIdx.x;
    const int lane = threadIdx.x;

    const float px = pts[i * 3 + 0];
    const float py = pts[i * 3 + 1];
    const float pz = pts[i * 3 + 2];

    // 16 distances per lane, registers only (static indices).
    float v[16];
    int c0 = 0, c1 = 0, c2 = 0;
    #pragma unroll
    for (int q = 0; q < 16; ++q) {
        const int j = lane + q * 64;              // coalesced across lanes
        // exact rounding, no fma contraction: ((dx*dx + dy*dy) + dz*dz)
        float dx = __fsub_rn(px, pts[j * 3 + 0]);
        float dy = __fsub_rn(py, pts[j * 3 + 1]);
        float dz = __fsub_rn(pz, pts[j * 3 + 2]);
        float d2 = __fadd_rn(__fadd_rn(__fmul_rn(dx, dx), __fmul_rn(dy, dy)),
                             __fmul_rn(dz, dz));
        float d = __fsqrt_rn(d2 > 0.0f ? d2 : 1e-12f);   // _safe_sqrt
        v[q] = d;
        c0 += (d < 0.1f);
        c1 += (d < 0.2f);
        c2 += (d < 0.4f);
    }

    // Pack counts into one ull (21-bit fields), single butterfly reduce.
    unsigned long long packed = (unsigned long long)c0
                              | ((unsigned long long)c1 << 21)
                              | ((unsigned long long)c2 << 42);
    #pragma unroll
    for (int off = 32; off > 0; off >>= 1) packed += __shfl_xor(packed, off);
    // every lane now holds the row totals

    // ---- per-lane bitonic sort of the 16 values (ascending), pure VALU ----
    #pragma unroll
    for (int k = 2; k <= 16; k <<= 1) {
        #pragma unroll
        for (int j = k >> 1; j > 0; j >>= 1) {
            #pragma unroll
            for (int r = 0; r < 16; ++r) {
                const int l = r ^ j;
                if (l > r) {
                    const bool up = ((r & k) == 0);
                    float lo = fminf(v[r], v[l]);
                    float hi = fmaxf(v[r], v[l]);
                    v[r] = up ? lo : hi;
                    v[l] = up ? hi : lo;
                }
            }
        }
    }

    // ---- pad to sorted-32, butterfly keep-min-32 merge across 64 lanes ----
    float s[32];
    #pragma unroll
    for (int r = 0; r < 16; ++r) { s[r] = v[r]; s[16 + r] = 3.0e38f; }

    #pragma unroll
    for (int step = 1; step < 64; step <<= 1) {
        float o[32];
        #pragma unroll
        for (int r = 0; r < 32; ++r) o[r] = __shfl_xor(s[r], step);
        // bitonic halver: lower half of [s, reverse(o)] = smallest 32 (bitonic)
        float m[32];
        #pragma unroll
        for (int r = 0; r < 32; ++r) m[r] = fminf(s[r], o[31 - r]);
        // bitonic clean -> ascending
        #pragma unroll
        for (int j = 16; j > 0; j >>= 1) {
            #pragma unroll
            for (int r = 0; r < 32; ++r) {
                const int l = r ^ j;
                if (l > r) {
                    float lo = fminf(m[r], m[l]);
                    float hi = fmaxf(m[r], m[l]);
                    m[r] = lo;
                    m[l] = hi;
                }
            }
        }
        #pragma unroll
        for (int r = 0; r < 32; ++r) s[r] = m[r];
    }
    // s[0..31]: global sorted 32 smallest (s[0] = self), identical in all lanes

    // ---- entropies over ranks 1..k — pure per-lane VALU, static indices ----
    const int kvv[3] = {5, 10, 25};
    float E[3];
    #pragma unroll
    for (int q = 0; q < 3; ++q) {
        const int k = kvv[q];
        float S = 0.0f;
        #pragma unroll
        for (int r = 1; r <= 25; ++r) if (r <= k) S += s[r];
        float Ee = 0.0f;
        #pragma unroll
        for (int r = 1; r <= 25; ++r) if (r <= k) {
            float p = s[r] / S;
            Ee -= p * logf(p + 1e-10f);
        }
        E[q] = Ee;
    }

    if (lane == 0) {
        ent[i * 3 + 0] = E[0];
        ent[i * 3 + 1] = E[1];
        ent[i * 3 + 2] = E[2];
        const float scl[3] = {0.1f, 0.2f, 0.4f};
        unsigned int cc[3] = {(unsigned int)(packed & 0x1FFFFF),
                              (unsigned int)((packed >> 21) & 0x1FFFFF),
                              (unsigned int)(packed >> 42)};
        #pragma unroll
        for (int s2 = 0; s2 < 3; ++s2) {
            float sv  = scl[s2];
            float vol = __fmul_rn((float)(4.0 / 3.0 * M_PI),
                                  __fmul_rn(__fmul_rn(sv, sv), sv));
            density[i * 3 + s2] = (float)cc[s2] / vol;
            icnt[i * 3 + s2] = cc[s2];
        }
    }
}

// ---------------------------------------------------------------------------
// Kernel B: embed only. 64 blocks x 256 thr; wave 0 reduces the 1024x3
// integer counts -> exact S1,S2; each wave embeds 4 rows -> svec (global).
// ---------------------------------------------------------------------------
__global__ __launch_bounds__(256) void k_embed(const float* __restrict__ density,
                                               const float* __restrict__ ent,
                                               const unsigned int* __restrict__ icnt,
                                               const float* __restrict__ Wm,
                                               const float* __restrict__ bm,
                                               const float* __restrict__ Wl,
                                               const float* __restrict__ bl,
                                               float* __restrict__ svec) {
    __shared__ double sS[6];           // S1[0..2], S2[0..2]
    const int c    = blockIdx.x;       // chunk of 16 rows
    const int t    = threadIdx.x;
    const int lane = t & 63;
    const int w    = t >> 6;

    // wave 0: exact integer sums over all rows (lane owns rows lane*16..+15)
    if (w == 0) {
        unsigned int sa0 = 0, sa1 = 0, sa2 = 0, sb0 = 0, sb1 = 0, sb2 = 0;
        #pragma unroll
        for (int r = 0; r < 16; ++r) {
            const int row = lane * 16 + r;
            unsigned int c0 = icnt[row * 3 + 0];
            unsigned int c1 = icnt[row * 3 + 1];
            unsigned int c2 = icnt[row * 3 + 2];
            sa0 += c0; sa1 += c1; sa2 += c2;
            sb0 += c0 * c0; sb1 += c1 * c1; sb2 += c2 * c2;
        }
        #pragma unroll
        for (int off = 32; off > 0; off >>= 1) {
            sa0 += __shfl_xor(sa0, off); sa1 += __shfl_xor(sa1, off);
            sa2 += __shfl_xor(sa2, off); sb0 += __shfl_xor(sb0, off);
            sb1 += __shfl_xor(sb1, off); sb2 += __shfl_xor(sb2, off);
        }
        if (lane == 0) {
            const float scl[3] = {0.1f, 0.2f, 0.4f};
            unsigned int A[3] = {sa0, sa1, sa2};
            unsigned int B[3] = {sb0, sb1, sb2};
            #pragma unroll
            for (int s = 0; s < 3; ++s) {
                float sv   = scl[s];
                float volf = __fmul_rn((float)(4.0 / 3.0 * M_PI),
                                       __fmul_rn(__fmul_rn(sv, sv), sv));
                double vold = (double)volf;
                sS[s]     = (double)A[s] / vold;
                sS[3 + s] = (double)B[s] / (vold * vold);
            }
        }
    }
    __syncthreads();

    double S1[3], S2[3];
    #pragma unroll
    for (int s = 0; s < 3; ++s) { S1[s] = sS[s]; S2[s] = sS[3 + s]; }

    #pragma unroll
    for (int kk = 0; kk < 4; ++kk) {
        const int row = 16 * c + 4 * w + kk;

        // mdve = l2norm([density(3), gradient(3)])
        float m6[6];
        double nrm6 = 0.0;
        #pragma unroll
        for (int s = 0; s < 3; ++s) {
            float d = density[row * 3 + s];
            m6[s] = d;
            double dd = (double)d;
            double g2 = 1024.0 * dd * dd - 2.0 * dd * S1[s] + S2[s];
            m6[3 + s] = (float)sqrt(g2 > 0.0 ? g2 : 1e-12);
        }
        #pragma unroll
        for (int s = 0; s < 6; ++s) nrm6 += (double)m6[s] * (double)m6[s];
        float inv6 = 1.0f / fmaxf((float)sqrt(nrm6), 1e-12f);
        #pragma unroll
        for (int s = 0; s < 6; ++s) m6[s] *= inv6;

        // lgee = l2norm(entropies(3))
        float l3[3];
        double nrm3 = 0.0;
        #pragma unroll
        for (int s = 0; s < 3; ++s) {
            l3[s] = ent[row * 3 + s];
            nrm3 += (double)l3[s] * (double)l3[s];
        }
        float inv3 = 1.0f / fmaxf((float)sqrt(nrm3), 1e-12f);
        #pragma unroll
        for (int s = 0; s < 3; ++s) l3[s] *= inv3;

        // y = l2norm(mdve @ Wm + bm) over the 64 hidden units (one wave)
        float y = bm[lane];
        #pragma unroll
        for (int s = 0; s < 6; ++s) y += m6[s] * Wm[s * HID + lane];
        float yy = y * y;
        #pragma unroll
        for (int off = 32; off > 0; off >>= 1) yy += __shfl_xor(yy, off);
        y *= 1.0f / fmaxf(sqrtf(yy), 1e-12f);

        // z = l2norm(lgee @ Wl + bl)
        float z = bl[lane];
        #pragma unroll
        for (int s = 0; s < 3; ++s) z += l3[s] * Wl[s * HID + lane];
        float zz = z * z;
        #pragma unroll
        for (int off = 32; off > 0; off >>= 1) zz += __shfl_xor(zz, off);
        z *= 1.0f / fmaxf(sqrtf(zz), 1e-12f);

        svec[row * HID + lane] = y + z;
    }
}

// ---------------------------------------------------------------------------
// Kernel C: PURE broadcast — sequential grid-stride write stream; source
// index is loop-invariant per thread (stride % mask+1 == 0) -> hoisted load.
// ---------------------------------------------------------------------------
__global__ __launch_bounds__(256) void k_bcast(const v4f* __restrict__ s4,
                                               v4f* __restrict__ out) {
    const int total = (NPTS * NPTS * HID) / 4;       // 16,777,216 v4f
    const int mask  = (NPTS * HID) / 4 - 1;          // 16383
    int idx = blockIdx.x * 256 + threadIdx.x;
    const int stride = gridDim.x * 256;
    for (; idx < total; idx += stride) {
        out[idx] = s4[idx & mask];
    }
}

extern "C" void kernel_launch(void* const* d_in, const int* in_sizes, int n_in,
                              void* d_out, int out_size, void* d_ws, size_t ws_size,
                              hipStream_t stream) {
    const float* pts = (const float*)d_in[0];
    // d_in[1], d_in[2] (W_rtdie, b_rtdie) do not affect the output.
    const float* Wm = (const float*)d_in[3];
    const float* bm = (const float*)d_in[4];
    const float* Wl = (const float*)d_in[5];
    const float* bl = (const float*)d_in[6];

    char* ws = (char*)d_ws;
    float*        density = (float*)(ws);                 // 12288 B
    float*        entv    = (float*)(ws + 12288);         // 12288 B
    unsigned int* icnt    = (unsigned int*)(ws + 24576);  // 12288 B
    float*        svec    = (float*)(ws + 36864);         // 262144 B

    float* out = (float*)d_out;

    hipLaunchKernelGGL(k_rows, dim3(NPTS), dim3(64), 0, stream,
                       pts, density, entv, icnt);
    hipLaunchKernelGGL(k_embed, dim3(64), dim3(256), 0, stream,
                       density, entv, icnt, Wm, bm, Wl, bl, svec);
    hipLaunchKernelGGL(k_bcast, dim3(2048), dim3(256), 0, stream,
                       (const v4f*)svec, (v4f*)out);
}

// Round 14
// 68.472 us; speedup vs baseline: 2.3554x; 1.0193x over previous
//
#include <hip/hip_runtime.h>
#include <math.h>

#define NPTS 1024
#define HID 64

typedef float v4f __attribute__((ext_vector_type(4)));

// ---------------------------------------------------------------------------
// Kernel A: ONE WAVE per row i. 16 distances/lane (exact fp32 on the
// density-count path). Selection of the 26 smallest via per-lane bitonic
// sort(16) + 6-step butterfly keep-min-32 merge (value multiset — exact).
// Every lane ends with the global sorted 32 smallest in registers; entropies
// are then pure per-lane VALU. Dependent-shfl depth: 6.
// ---------------------------------------------------------------------------
__global__ __launch_bounds__(64) void k_rows(const float* __restrict__ pts,
                                             float* __restrict__ density,
                                             float* __restrict__ ent,
                                             unsigned int* __restrict__ icnt) {
    const int i    = blockIdx.x;
    const int lane = threadIdx.x;

    const float px = pts[i * 3 + 0];
    const float py = pts[i * 3 + 1];
    const float pz = pts[i * 3 + 2];

    // 16 distances per lane, registers only (static indices).
    float v[16];
    int c0 = 0, c1 = 0, c2 = 0;
    #pragma unroll
    for (int q = 0; q < 16; ++q) {
        const int j = lane + q * 64;              // coalesced across lanes
        // exact rounding, no fma contraction: ((dx*dx + dy*dy) + dz*dz)
        float dx = __fsub_rn(px, pts[j * 3 + 0]);
        float dy = __fsub_rn(py, pts[j * 3 + 1]);
        float dz = __fsub_rn(pz, pts[j * 3 + 2]);
        float d2 = __fadd_rn(__fadd_rn(__fmul_rn(dx, dx), __fmul_rn(dy, dy)),
                             __fmul_rn(dz, dz));
        float d = __fsqrt_rn(d2 > 0.0f ? d2 : 1e-12f);   // _safe_sqrt
        v[q] = d;
        c0 += (d < 0.1f);
        c1 += (d < 0.2f);
        c2 += (d < 0.4f);
    }

    // Pack counts into one ull (21-bit fields), single butterfly reduce.
    unsigned long long packed = (unsigned long long)c0
                              | ((unsigned long long)c1 << 21)
                              | ((unsigned long long)c2 << 42);
    #pragma unroll
    for (int off = 32; off > 0; off >>= 1) packed += __shfl_xor(packed, off);
    // every lane now holds the row totals

    // ---- per-lane bitonic sort of the 16 values (ascending), pure VALU ----
    #pragma unroll
    for (int k = 2; k <= 16; k <<= 1) {
        #pragma unroll
        for (int j = k >> 1; j > 0; j >>= 1) {
            #pragma unroll
            for (int r = 0; r < 16; ++r) {
                const int l = r ^ j;
                if (l > r) {
                    const bool up = ((r & k) == 0);
                    float lo = fminf(v[r], v[l]);
                    float hi = fmaxf(v[r], v[l]);
                    v[r] = up ? lo : hi;
                    v[l] = up ? hi : lo;
                }
            }
        }
    }

    // ---- pad to sorted-32, butterfly keep-min-32 merge across 64 lanes ----
    float s[32];
    #pragma unroll
    for (int r = 0; r < 16; ++r) { s[r] = v[r]; s[16 + r] = 3.0e38f; }

    #pragma unroll
    for (int step = 1; step < 64; step <<= 1) {
        float o[32];
        #pragma unroll
        for (int r = 0; r < 32; ++r) o[r] = __shfl_xor(s[r], step);
        // bitonic halver: lower half of [s, reverse(o)] = smallest 32 (bitonic)
        float m[32];
        #pragma unroll
        for (int r = 0; r < 32; ++r) m[r] = fminf(s[r], o[31 - r]);
        // bitonic clean -> ascending
        #pragma unroll
        for (int j = 16; j > 0; j >>= 1) {
            #pragma unroll
            for (int r = 0; r < 32; ++r) {
                const int l = r ^ j;
                if (l > r) {
                    float lo = fminf(m[r], m[l]);
                    float hi = fmaxf(m[r], m[l]);
                    m[r] = lo;
                    m[l] = hi;
                }
            }
        }
        #pragma unroll
        for (int r = 0; r < 32; ++r) s[r] = m[r];
    }
    // s[0..31]: global sorted 32 smallest (s[0] = self), identical in all lanes

    // ---- entropies over ranks 1..k — pure per-lane VALU, static indices ----
    const int kvv[3] = {5, 10, 25};
    float E[3];
    #pragma unroll
    for (int q = 0; q < 3; ++q) {
        const int k = kvv[q];
        float S = 0.0f;
        #pragma unroll
        for (int r = 1; r <= 25; ++r) if (r <= k) S += s[r];
        float Ee = 0.0f;
        #pragma unroll
        for (int r = 1; r <= 25; ++r) if (r <= k) {
            float p = s[r] / S;
            Ee -= p * logf(p + 1e-10f);
        }
        E[q] = Ee;
    }

    if (lane == 0) {
        ent[i * 3 + 0] = E[0];
        ent[i * 3 + 1] = E[1];
        ent[i * 3 + 2] = E[2];
        const float scl[3] = {0.1f, 0.2f, 0.4f};
        unsigned int cc[3] = {(unsigned int)(packed & 0x1FFFFF),
                              (unsigned int)((packed >> 21) & 0x1FFFFF),
                              (unsigned int)(packed >> 42)};
        #pragma unroll
        for (int s2 = 0; s2 < 3; ++s2) {
            float sv  = scl[s2];
            float vol = __fmul_rn((float)(4.0 / 3.0 * M_PI),
                                  __fmul_rn(__fmul_rn(sv, sv), sv));
            density[i * 3 + s2] = (float)cc[s2] / vol;
            icnt[i * 3 + s2] = cc[s2];
        }
    }
}

// ---------------------------------------------------------------------------
// Kernel B: fused sums + embed + broadcast (2-node graph). Wave 0 reduces
// the 1024x3 integer counts -> exact S1,S2 in LDS. Block (c,g): embeds
// svec chunk c (16 rows x 64 hidden) into 4 KB LDS, then 32 coalesced
// 4 KB stores to i-group g.
// ---------------------------------------------------------------------------
__global__ __launch_bounds__(256) void k_bcast(const float* __restrict__ density,
                                               const float* __restrict__ ent,
                                               const unsigned int* __restrict__ icnt,
                                               const float* __restrict__ Wm,
                                               const float* __restrict__ bm,
                                               const float* __restrict__ Wl,
                                               const float* __restrict__ bl,
                                               v4f* __restrict__ out) {
    __shared__ float  s_lds[16 * HID];
    __shared__ double sS[6];           // S1[0..2], S2[0..2]
    const int b    = blockIdx.x;
    const int c    = b & 63;           // 64 chunks of 16 rows
    const int g    = b >> 6;           // 32 i-groups of 32 rows
    const int t    = threadIdx.x;
    const int lane = t & 63;
    const int w    = t >> 6;

    // wave 0: exact integer sums over all rows (lane owns rows lane*16..+15)
    if (w == 0) {
        unsigned int sa0 = 0, sa1 = 0, sa2 = 0, sb0 = 0, sb1 = 0, sb2 = 0;
        #pragma unroll
        for (int r = 0; r < 16; ++r) {
            const int row = lane * 16 + r;
            unsigned int c0 = icnt[row * 3 + 0];
            unsigned int c1 = icnt[row * 3 + 1];
            unsigned int c2 = icnt[row * 3 + 2];
            sa0 += c0; sa1 += c1; sa2 += c2;
            sb0 += c0 * c0; sb1 += c1 * c1; sb2 += c2 * c2;
        }
        #pragma unroll
        for (int off = 32; off > 0; off >>= 1) {
            sa0 += __shfl_xor(sa0, off); sa1 += __shfl_xor(sa1, off);
            sa2 += __shfl_xor(sa2, off); sb0 += __shfl_xor(sb0, off);
            sb1 += __shfl_xor(sb1, off); sb2 += __shfl_xor(sb2, off);
        }
        if (lane == 0) {
            const float scl[3] = {0.1f, 0.2f, 0.4f};
            unsigned int A[3] = {sa0, sa1, sa2};
            unsigned int B[3] = {sb0, sb1, sb2};
            #pragma unroll
            for (int s = 0; s < 3; ++s) {
                float sv   = scl[s];
                float volf = __fmul_rn((float)(4.0 / 3.0 * M_PI),
                                       __fmul_rn(__fmul_rn(sv, sv), sv));
                double vold = (double)volf;
                sS[s]     = (double)A[s] / vold;
                sS[3 + s] = (double)B[s] / (vold * vold);
            }
        }
    }
    __syncthreads();

    double S1[3], S2[3];
    #pragma unroll
    for (int s = 0; s < 3; ++s) { S1[s] = sS[s]; S2[s] = sS[3 + s]; }

    #pragma unroll
    for (int kk = 0; kk < 4; ++kk) {
        const int row = 16 * c + 4 * w + kk;

        // mdve = l2norm([density(3), gradient(3)])
        float m6[6];
        double nrm6 = 0.0;
        #pragma unroll
        for (int s = 0; s < 3; ++s) {
            float d = density[row * 3 + s];
            m6[s] = d;
            double dd = (double)d;
            double g2 = 1024.0 * dd * dd - 2.0 * dd * S1[s] + S2[s];
            m6[3 + s] = (float)sqrt(g2 > 0.0 ? g2 : 1e-12);
        }
        #pragma unroll
        for (int s = 0; s < 6; ++s) nrm6 += (double)m6[s] * (double)m6[s];
        float inv6 = 1.0f / fmaxf((float)sqrt(nrm6), 1e-12f);
        #pragma unroll
        for (int s = 0; s < 6; ++s) m6[s] *= inv6;

        // lgee = l2norm(entropies(3))
        float l3[3];
        double nrm3 = 0.0;
        #pragma unroll
        for (int s = 0; s < 3; ++s) {
            l3[s] = ent[row * 3 + s];
            nrm3 += (double)l3[s] * (double)l3[s];
        }
        float inv3 = 1.0f / fmaxf((float)sqrt(nrm3), 1e-12f);
        #pragma unroll
        for (int s = 0; s < 3; ++s) l3[s] *= inv3;

        // y = l2norm(mdve @ Wm + bm) over the 64 hidden units (one wave)
        float y = bm[lane];
        #pragma unroll
        for (int s = 0; s < 6; ++s) y += m6[s] * Wm[s * HID + lane];
        float yy = y * y;
        #pragma unroll
        for (int off = 32; off > 0; off >>= 1) yy += __shfl_xor(yy, off);
        y *= 1.0f / fmaxf(sqrtf(yy), 1e-12f);

        // z = l2norm(lgee @ Wl + bl)
        float z = bl[lane];
        #pragma unroll
        for (int s = 0; s < 3; ++s) z += l3[s] * Wl[s * HID + lane];
        float zz = z * z;
        #pragma unroll
        for (int off = 32; off > 0; off >>= 1) zz += __shfl_xor(zz, off);
        z *= 1.0f / fmaxf(sqrtf(zz), 1e-12f);

        s_lds[(4 * w + kk) * HID + lane] = y + z;
    }
    __syncthreads();

    const v4f val = *(const v4f*)&s_lds[4 * t];   // registers

    v4f* dst = out + (size_t)(g * 32) * (NPTS * HID / 4) + c * 256 + t;
    #pragma unroll 4
    for (int ii = 0; ii < 32; ++ii) {
        *dst = val;
        dst += NPTS * HID / 4;                    // next i: +16384 v4f
    }
}

extern "C" void kernel_launch(void* const* d_in, const int* in_sizes, int n_in,
                              void* d_out, int out_size, void* d_ws, size_t ws_size,
                              hipStream_t stream) {
    const float* pts = (const float*)d_in[0];
    // d_in[1], d_in[2] (W_rtdie, b_rtdie) do not affect the output.
    const float* Wm = (const float*)d_in[3];
    const float* bm = (const float*)d_in[4];
    const float* Wl = (const float*)d_in[5];
    const float* bl = (const float*)d_in[6];

    char* ws = (char*)d_ws;
    float*        density = (float*)(ws);                 // 12288 B
    float*        entv    = (float*)(ws + 12288);         // 12288 B
    unsigned int* icnt    = (unsigned int*)(ws + 24576);  // 12288 B

    float* out = (float*)d_out;

    hipLaunchKernelGGL(k_rows, dim3(NPTS), dim3(64), 0, stream,
                       pts, density, entv, icnt);
    hipLaunchKernelGGL(k_bcast, dim3(64 * 32), dim3(256), 0, stream,
                       density, entv, icnt, Wm, bm, Wl, bl, (v4f*)out);
}